// Round 1
// baseline (549.381 us; speedup 1.0000x reference)
//
#include <hip/hip_runtime.h>

#define TOK    64
#define NOUT   8192
#define KTOT   8192
#define KQ     7936
#define KFP    256
#define NWAVE  8
#define WCH    (KTOT / NWAVE)    // 1024 K-columns per wave
#define NS     (WCH / 32)        // 32 iters of K=32 per wave

typedef float f32x4 __attribute__((ext_vector_type(4)));
typedef short s16x8 __attribute__((ext_vector_type(8)));

__device__ __forceinline__ unsigned short f2bf(float f) {
    unsigned int u = __float_as_uint(f);
    u += 0x7fffu + ((u >> 16) & 1u);
    return (unsigned short)(u >> 16);
}

// Permute+cast input to bf16. out-init dropped: epilogue is now non-atomic.
__global__ void prep(const float* __restrict__ inp, const int* __restrict__ invp,
                     unsigned short* __restrict__ xp) {
    int idx = blockIdx.x * blockDim.x + threadIdx.x;
    int j = idx & (KTOT - 1);
    xp[(idx >> 13) * KTOT + invp[j]] = f2bf(inp[idx]);
}

// Wave = (16-col n-tile, 1024-wide K-chunk). Weights global->reg (zero reuse,
// so no LDS staging, no main-loop barriers). Quantize ONCE per element, reuse
// B-frag across 4 M-tile MFMAs (4 accumulators). 8 waves cover K=8192; LDS
// used only for the 8-way partial reduce; bias fused in the final store.
__global__ __launch_bounds__(512, 4) void sasut_gemm(
    const unsigned short* __restrict__ xp,   // [64][8192] bf16 permuted input
    const float* __restrict__ qw,            // [8192][7936]
    const float* __restrict__ fpw,           // [8192][256]
    const float* __restrict__ alpha,         // [8192]
    const float* __restrict__ noise,         // [8192][7936]
    const float* __restrict__ bias,          // [8192]
    float* __restrict__ out)                 // [64][8192]
{
    __shared__ float red[NWAVE][4][16][17];  // 34.8 KB, epilogue only
    const int tid  = threadIdx.x;
    const int w    = tid >> 6;
    const int lane = tid & 63;
    const int nloc = lane & 15;              // weight row / output col in tile
    const int quad = lane >> 4;
    const int nbase = blockIdx.x * 16;
    const int kw   = w * WCH;                // wave's K start (KQ boundary is
                                             // iter-aligned: 7936-7168=768=24*32)

    const int row = nbase + nloc;
    const float a_s  = alpha[row];
    const float c_s  = a_s * (1.0f / 14.0f); // 0.5*alpha/QMAX (QMAX=7)
    const float na_s = -a_s;

    // B-frag source: lane holds k = kw + s*32 + quad*8 + (0..7) of weight row.
    const float* qp  = qw    + (size_t)row * KQ  + kw + quad * 8;
    const float* np  = noise + (size_t)row * KQ  + kw + quad * 8;
    const float* fpq = fpw   + (size_t)row * KFP + quad * 8;

    // A-frag sources: token rows mt*16+nloc at the same k window (L2-resident).
    const unsigned short* x0 = xp + (size_t)nloc * KTOT + kw + quad * 8;
    const unsigned short* x1 = x0 + (size_t)16 * KTOT;
    const unsigned short* x2 = x0 + (size_t)32 * KTOT;
    const unsigned short* x3 = x0 + (size_t)48 * KTOT;

    f32x4 acc0 = {0.f, 0.f, 0.f, 0.f};
    f32x4 acc1 = acc0, acc2 = acc0, acc3 = acc0;

    #pragma unroll 2
    for (int s = 0; s < NS; ++s) {
        const int k_ = kw + s * 32;          // wave-uniform
        s16x8 a0f = *(const s16x8*)(x0 + s * 32);
        s16x8 a1f = *(const s16x8*)(x1 + s * 32);
        s16x8 a2f = *(const s16x8*)(x2 + s * 32);
        s16x8 a3f = *(const s16x8*)(x3 + s * 32);
        s16x8 bf;
        if (k_ < KQ) {                       // quantized+noised weight path
            f32x4 qa = *(const f32x4*)(qp + s * 32);
            f32x4 qc = *(const f32x4*)(qp + s * 32 + 4);
            f32x4 na = *(const f32x4*)(np + s * 32);
            f32x4 nc = *(const f32x4*)(np + s * 32 + 4);
            #pragma unroll
            for (int j = 0; j < 8; ++j) {
                float wv = (j < 4) ? qa[j] : qc[j - 4];
                float nz = (j < 4) ? na[j] : nc[j - 4];
                float t = fmaf(nz, c_s, wv);
                t = (wv >= a_s)  ? a_s  : t;
                t = (wv <= na_s) ? na_s : t;
                bf[j] = (short)f2bf(t);
            }
        } else {                             // fp outlier path (no noise)
            const float* f_ = fpq + (k_ - KQ);
            f32x4 qa = *(const f32x4*)(f_);
            f32x4 qc = *(const f32x4*)(f_ + 4);
            #pragma unroll
            for (int j = 0; j < 8; ++j) {
                float wv = (j < 4) ? qa[j] : qc[j - 4];
                bf[j] = (short)f2bf(wv);
            }
        }
        acc0 = __builtin_amdgcn_mfma_f32_16x16x32_bf16(a0f, bf, acc0, 0, 0, 0);
        acc1 = __builtin_amdgcn_mfma_f32_16x16x32_bf16(a1f, bf, acc1, 0, 0, 0);
        acc2 = __builtin_amdgcn_mfma_f32_16x16x32_bf16(a2f, bf, acc2, 0, 0, 0);
        acc3 = __builtin_amdgcn_mfma_f32_16x16x32_bf16(a3f, bf, acc3, 0, 0, 0);
    }

    // 8-way cross-wave reduction in LDS, bias fused, non-atomic store.
    #pragma unroll
    for (int r = 0; r < 4; ++r) {
        red[w][0][quad * 4 + r][nloc] = acc0[r];
        red[w][1][quad * 4 + r][nloc] = acc1[r];
        red[w][2][quad * 4 + r][nloc] = acc2[r];
        red[w][3][quad * 4 + r][nloc] = acc3[r];
    }
    __syncthreads();
    #pragma unroll
    for (int rep = 0; rep < 2; ++rep) {
        int e   = tid + rep * 512;           // 4 mtiles x 16 x 16 = 1024 outs
        int m   = e >> 8;
        int tl  = (e >> 4) & 15;
        int col = e & 15;
        float v = bias[nbase + col];
        #pragma unroll
        for (int ww = 0; ww < NWAVE; ++ww) v += red[ww][m][tl][col];
        out[(size_t)(m * 16 + tl) * NOUT + nbase + col] = v;
    }
}

extern "C" void kernel_launch(void* const* d_in, const int* in_sizes, int n_in,
                              void* d_out, int out_size, void* d_ws, size_t ws_size,
                              hipStream_t stream) {
    const float* inp   = (const float*)d_in[0];
    const float* qw    = (const float*)d_in[1];
    const float* fpw   = (const float*)d_in[2];
    const float* alpha = (const float*)d_in[3];
    const float* bias  = (const float*)d_in[4];
    const float* noise = (const float*)d_in[5];
    const int*   invp  = (const int*)d_in[6];
    float* out = (float*)d_out;
    unsigned short* xp = (unsigned short*)d_ws;   // 1 MB scratch

    prep<<<(TOK * KTOT) / 256, 256, 0, stream>>>(inp, invp, xp);
    sasut_gemm<<<512, 512, 0, stream>>>(xp, qw, fpw, alpha, noise, bias, out);
}

// Round 2
// 515.874 us; speedup vs baseline: 1.0650x; 1.0650x over previous
//
#include <hip/hip_runtime.h>

#define TOK   64
#define NOUT  8192
#define KTOT  8192
#define KQ    7936
#define KFP   256
#define SK    256               // K-floats per step
#define NS    32                // 31 quant steps + 1 fp step (31*256 == KQ)

typedef float f32x4 __attribute__((ext_vector_type(4)));
typedef short s16x8 __attribute__((ext_vector_type(8)));

__device__ __forceinline__ unsigned short f2bf(float f) {
    unsigned int u = __float_as_uint(f);
    u += 0x7fffu + ((u >> 16) & 1u);
    return (unsigned short)(u >> 16);
}

__device__ __forceinline__ void gl16(const void* g, void* l) {
    __builtin_amdgcn_global_load_lds(
        (const __attribute__((address_space(1))) void*)g,
        (__attribute__((address_space(3))) void*)l, 16, 0, 0);
}

#define WAITV(n) asm volatile("s_waitcnt vmcnt(" #n ")" ::: "memory")

// Repack permuted bf16 input MFMA-A-friendly: xq[kg][t][j] = x_perm[t][kg*8+j].
// A-frag global loads become 4x256B contiguous segments instead of 16x16B scatter.
__global__ void prep(const float* __restrict__ inp, const int* __restrict__ invp,
                     unsigned short* __restrict__ xq) {
    int idx = blockIdx.x * blockDim.x + threadIdx.x;
    int t = idx >> 13, c = idx & (KTOT - 1);
    int p = invp[c];
    xq[(size_t)((p >> 3) * TOK + t) * 8 + (p & 7)] = f2bf(inp[idx]);
}

// Block = 16 output cols, full K=8192. 8 waves; per 256-float step wave w owns
// K-slice w*32: quantizes ONCE, feeds 4 M-tile MFMAs. Weights stream via
// global_load_lds (coalesced 1KB/instr) into a 2-deep buffer driven by raw
// s_barrier + counted vmcnt (prefetch never drained). Epilogue: 8-way K reduce
// in LDS + bias, non-atomic store.
__global__ __launch_bounds__(512, 4) void sasut_gemm(
    const unsigned short* __restrict__ xq,   // [1024][64][8] bf16
    const float* __restrict__ qw,            // [8192][7936]
    const float* __restrict__ fpw,           // [8192][256]
    const float* __restrict__ alpha,         // [8192]
    const float* __restrict__ noise,         // [8192][7936]
    const float* __restrict__ bias,          // [8192]
    float* __restrict__ out)                 // [64][8192]
{
    __shared__ __attribute__((aligned(16))) char smem[2 * 32768]; // q16K + n16K per buf
    const int tid  = threadIdx.x;
    const int w    = tid >> 6;
    const int lane = tid & 63;
    const int nloc = lane & 15;
    const int quad = lane >> 4;
    const int nbase = blockIdx.x * 16;

    const int row = nbase + nloc;
    const float a_s  = alpha[row];
    const float c_s  = a_s * (1.0f / 14.0f);  // 0.5*alpha/QMAX (QMAX=7)
    const float na_s = -a_s;

    // --- staging: wave w stages rows {2w, 2w+1} of q and n. LDS dest is linear
    // (base + lane*16, gload_lds constraint); XOR swizzle applied to the GLOBAL
    // source chunk so ds_read side can de-conflict (rule 21).
    const int rA = 2 * w, rB = 2 * w + 1;
    const size_t qoffA = (size_t)(nbase + rA) * KQ  + ((lane ^ (rA & 7)) << 2);
    const size_t qoffB = (size_t)(nbase + rB) * KQ  + ((lane ^ (rB & 7)) << 2);
    const size_t foffA = (size_t)(nbase + rA) * KFP + ((lane ^ (rA & 7)) << 2);
    const size_t foffB = (size_t)(nbase + rB) * KFP + ((lane ^ (rB & 7)) << 2);

    auto stage = [&](int s2) {
        char* b = smem + (s2 & 1) * 32768;
        if (s2 < NS - 1) {
            const float* q = qw    + (size_t)s2 * SK;
            const float* n = noise + (size_t)s2 * SK;
            gl16(q + qoffA, b + rA * 1024);
            gl16(q + qoffB, b + rB * 1024);
            gl16(n + qoffA, b + 16384 + rA * 1024);
            gl16(n + qoffB, b + 16384 + rB * 1024);
        } else {                              // fp step: 2 loads only
            gl16(fpw + foffA, b + rA * 1024);
            gl16(fpw + foffB, b + rB * 1024);
        }
    };

    // --- consume-side constants
    const int sw  = nloc & 7;
    const int c0  = w * 8 + quad * 2;                  // 16B-chunk idx in row
    const int cc0 = ((c0     ^ sw) << 2);              // float offsets (const)
    const int cc1 = (((c0+1) ^ sw) << 2);

    // A-frag base: token m*16+nloc, kg = s*32 + w*4 + quad
    const unsigned short* xA = xq + (size_t)(w * 4 + quad) * 512 + nloc * 8;

    // --- prologue: 2-deep pipeline
    stage(0);
    s16x8 a0 = *(const s16x8*)(xA);
    s16x8 a1 = *(const s16x8*)(xA + 128);
    s16x8 a2 = *(const s16x8*)(xA + 256);
    s16x8 a3 = *(const s16x8*)(xA + 384);
    stage(1);

    f32x4 acc0 = {0.f, 0.f, 0.f, 0.f};
    f32x4 acc1 = acc0, acc2 = acc0, acc3 = acc0;

    for (int s = 0; s < NS; ++s) {
        // Counted wait: retire step-s staging, keep step-s+1 staging in flight.
        // (outstanding at entry: stage(s)[4|2] + A(s)[4] + stage(s+1)[4|2])
        if (s == 0)          WAITV(4);   // robust to prologue reordering
        else if (s < NS - 2) WAITV(8);
        else if (s == NS-2)  WAITV(6);   // stage(31) has only 2 loads
        else                 WAITV(4);
        __builtin_amdgcn_s_barrier();    // step-s data visible to all waves

        // prefetch next A-frags (L2-resident; compiler manages their waits)
        s16x8 b0 = a0, b1 = a1, b2 = a2, b3 = a3;
        if (s + 1 < NS) {
            const unsigned short* p = xA + (size_t)(s + 1) * 16384;
            b0 = *(const s16x8*)(p);
            b1 = *(const s16x8*)(p + 128);
            b2 = *(const s16x8*)(p + 256);
            b3 = *(const s16x8*)(p + 384);
        }

        const float* qb = (const float*)(smem + (s & 1) * 32768) + nloc * 256;
        f32x4 qa = *(const f32x4*)(qb + cc0);
        f32x4 qc = *(const f32x4*)(qb + cc1);
        s16x8 bfv;
        if (s < NS - 1) {                    // quant+noise+clamp path
            const float* nb = qb + 4096;
            f32x4 na = *(const f32x4*)(nb + cc0);
            f32x4 nc = *(const f32x4*)(nb + cc1);
            #pragma unroll
            for (int j = 0; j < 8; ++j) {
                float wv = (j < 4) ? qa[j] : qc[j - 4];
                float nz = (j < 4) ? na[j] : nc[j - 4];
                float t = fmaf(nz, c_s, wv);
                t = (wv >= a_s)  ? a_s  : t;
                t = (wv <= na_s) ? na_s : t;
                bfv[j] = (short)f2bf(t);
            }
        } else {                             // fp outlier step
            #pragma unroll
            for (int j = 0; j < 8; ++j) {
                float wv = (j < 4) ? qa[j] : qc[j - 4];
                bfv[j] = (short)f2bf(wv);
            }
        }
        acc0 = __builtin_amdgcn_mfma_f32_16x16x32_bf16(a0, bfv, acc0, 0, 0, 0);
        acc1 = __builtin_amdgcn_mfma_f32_16x16x32_bf16(a1, bfv, acc1, 0, 0, 0);
        acc2 = __builtin_amdgcn_mfma_f32_16x16x32_bf16(a2, bfv, acc2, 0, 0, 0);
        acc3 = __builtin_amdgcn_mfma_f32_16x16x32_bf16(a3, bfv, acc3, 0, 0, 0);

        __builtin_amdgcn_s_barrier();        // all waves done reading buf s&1
        if (s + 2 < NS) stage(s + 2);        // overwrite buf s&1 for step s+2
        a0 = b0; a1 = b1; a2 = b2; a3 = b3;
    }

    // --- epilogue: 8-way cross-wave K reduction, bias fused, non-atomic store
    __syncthreads();
    float* red = (float*)smem;               // [8][4][16][17] = 34.8 KB
    #pragma unroll
    for (int r = 0; r < 4; ++r) {
        red[((w * 4 + 0) * 16 + quad * 4 + r) * 17 + nloc] = acc0[r];
        red[((w * 4 + 1) * 16 + quad * 4 + r) * 17 + nloc] = acc1[r];
        red[((w * 4 + 2) * 16 + quad * 4 + r) * 17 + nloc] = acc2[r];
        red[((w * 4 + 3) * 16 + quad * 4 + r) * 17 + nloc] = acc3[r];
    }
    __syncthreads();
    #pragma unroll
    for (int rep = 0; rep < 2; ++rep) {
        int e   = tid + rep * 512;           // 4 mtiles x 16 x 16 = 1024 outs
        int m   = e >> 8;
        int tl  = (e >> 4) & 15;
        int col = e & 15;
        float v = bias[nbase + col];
        #pragma unroll
        for (int ww = 0; ww < 8; ++ww)
            v += red[((ww * 4 + m) * 16 + tl) * 17 + col];
        out[(size_t)(m * 16 + tl) * NOUT + nbase + col] = v;
    }
}

extern "C" void kernel_launch(void* const* d_in, const int* in_sizes, int n_in,
                              void* d_out, int out_size, void* d_ws, size_t ws_size,
                              hipStream_t stream) {
    const float* inp   = (const float*)d_in[0];
    const float* qw    = (const float*)d_in[1];
    const float* fpw   = (const float*)d_in[2];
    const float* alpha = (const float*)d_in[3];
    const float* bias  = (const float*)d_in[4];
    const float* noise = (const float*)d_in[5];
    const int*   invp  = (const int*)d_in[6];
    float* out = (float*)d_out;
    unsigned short* xq = (unsigned short*)d_ws;   // 1 MB scratch

    prep<<<(TOK * KTOT) / 256, 256, 0, stream>>>(inp, invp, xq);
    sasut_gemm<<<NOUT / 16, 512, 0, stream>>>(xq, qw, fpw, alpha, noise, bias, out);
}